// Round 8
// baseline (331.312 us; speedup 1.0000x reference)
//
#include <hip/hip_runtime.h>
#include <hip/hip_bf16.h>
#include <stdint.h>

// Conv 3x3 SAME, NHWC fp32 in/out, implicit GEMM via bf16 MFMA.
// M = B*H*W = 100352, N = COUT = 256, K = 9*256 = 2304.
// Round 12: BK=128 as TWO r4-planes. The proven round-4 kernel (150 us,
// MfmaUtil 34.5) pays 2 barriers + a full drain per 64-wide K-step, 36x.
// Process K-steps two-at-a-time: plane 0 holds r4-step 2t, plane 1 holds
// 2t+1 (STAGE code byte-identical, dest/src offset only). One barrier pair
// per PAIR: sync -> read p0 -> MFMA p0 -> read p1 -> sync -> stage next
// pair -> MFMA p1. Barriers 72->36, drains 36->18. LDS 64 KB (2 blocks/CU).
// Staging granule, swizzle, MFMA order, epilogue, grid map: unchanged.

#define IMG_B 32
#define IMG_H 56
#define IMG_W 56
#define CIN   256
#define COUT  256
#define KDIM  2304          // 3*3*256
#define M_TOT 100352
#define HW    (IMG_H * IMG_W)
#define PW    58            // padded width
#define PHW   (PW * PW)     // 3364 padded pixels per image
#define BK    64            // k-elems per plane (r4 step)
#define ITERS 36            // r4 K-steps
#define ITER2 18            // paired iterations
#define PLANE_E (128 * BK)  // 8192 elems = 16 KB per plane
#define WT_BLOCKS  (KDIM * COUT / 256)       // 2304
#define INT_BLOCKS (IMG_B * IMG_H * 7)       // 12544
#define BORDER_PIX 228                       // per image: 58+58+56+56
#define BORDER_BLOCKS (IMG_B * BORDER_PIX * 32 / 256)   // 912

typedef __bf16 bf16_t;
typedef bf16_t bf16x8 __attribute__((ext_vector_type(8)));
typedef float  f32x4  __attribute__((ext_vector_type(4)));
typedef float  f32x16 __attribute__((ext_vector_type(16)));

typedef const __attribute__((address_space(1))) void GV;
typedef __attribute__((address_space(3))) void LV;

__device__ __forceinline__ void async16(const bf16_t* g, bf16_t* l) {
    // LDS dest = wave-uniform(l) + laneid*16; 16B per lane
    __builtin_amdgcn_global_load_lds((GV*)g, (LV*)l, 16, 0, 0);
}

// ---------- prep 1: interior copy fp32 NHWC -> bf16 padded [B][58][58][C] ----------
__global__ void prep_interior(const float* __restrict__ in, bf16_t* __restrict__ out) {
    const int bid   = blockIdx.x;
    const int chunk = bid % 7;
    const int rid   = bid / 7;            // 0 .. B*H-1
    const int b     = rid / IMG_H;
    const int y     = rid - b * IMG_H;
    const int e     = chunk * 2048 + threadIdx.x * 8;   // elem within row [0,14336)

    const float* s = in + ((((size_t)b * IMG_H + y) * IMG_W) << 8) + e;
    bf16_t*      d = out + (((size_t)b * PHW + (y + 1) * PW + 1) << 8) + e;

    const f32x4 a = *(const f32x4*)s;
    const f32x4 c = *(const f32x4*)(s + 4);
    bf16x8 v;
    #pragma unroll
    for (int k = 0; k < 4; ++k) { v[k] = (bf16_t)a[k]; v[4 + k] = (bf16_t)c[k]; }
    *(bf16x8*)d = v;
}

// ---------- prep 2: zero border pixels of the padded image ----------
__global__ void prep_border(bf16_t* __restrict__ out) {
    const int idx = blockIdx.x * 256 + threadIdx.x;
    const int p   = idx >> 5;             // border pixel id
    const int c0  = (idx & 31) << 3;
    const int b   = p / BORDER_PIX;
    const int j   = p - b * BORDER_PIX;
    int py, px;
    if      (j < 58)  { py = 0;            px = j;       }
    else if (j < 116) { py = 57;           px = j - 58;  }
    else if (j < 172) { py = j - 116 + 1;  px = 0;       }
    else              { py = j - 172 + 1;  px = 57;      }
    bf16x8 z = {};
    *(bf16x8*)(out + (((size_t)b * PHW + py * PW + px) << 8) + c0) = z;
}

// ---------- prep 3: HWIO f32 kernel[k][co] -> Wt bf16 [co][k] ----------
__global__ void prep_weights(const float* __restrict__ kern, bf16_t* __restrict__ wt) {
    int idx = blockIdx.x * 256 + threadIdx.x;          // 0 .. 2304*256-1
    int co  = idx / KDIM;
    int k   = idx - co * KDIM;
    wt[idx] = (bf16_t)kern[k * COUT + co];             // coalesced bf16 writes
}

// ---------- main conv: 128x128 tile, BK=128 via two r4-planes ----------

// stage r4-step (it1) of A and B into plane (h): byte-identical to r4's STAGE
// except the plane-base offset h*PLANE_E.
#define STAGE_P(it1, h) do { \
    const int tap_  = (it1) >> 2; \
    const int kh_   = tap_ / 3; \
    const int kw_   = tap_ - kh_ * 3; \
    const int koff_ = ((kh_ * PW + kw_) << 8) + (((it1) & 3) << 6); \
    const int woff_ = (it1) * BK; \
    _Pragma("unroll") \
    for (int i_ = 0; i_ < 4; ++i_) { \
        async16(asrc[i_] + koff_, alds[i_] + (h) * PLANE_E); \
        async16(bsrc[i_] + woff_, blds[i_] + (h) * PLANE_E); \
    } \
} while (0)

__global__ __launch_bounds__(256)
void conv_mfma_p(const bf16_t* __restrict__ P, const bf16_t* __restrict__ wt,
                 const float* __restrict__ bias, float* __restrict__ out)
{
    __shared__ bf16_t Al[2 * PLANE_E];   // 32 KB: planes 0,1
    __shared__ bf16_t Bl[2 * PLANE_E];   // 32 KB  (64 KB total -> 2 blocks/CU)

    const int tid  = threadIdx.x;
    const int wave = tid >> 6;
    const int lane = tid & 63;

    // XCD-contiguous tile mapping: blocks on one XCD cover 196 contiguous tiles
    const int bid   = blockIdx.x;
    const int tile  = (bid & 7) * 196 + (bid >> 3);
    const int ntile = tile & 1;
    const int mtile = tile >> 1;

    // ---- staging roles: per DMA issue, 8 rows x 8 segs of 16B per wave ----
    const int rl = lane >> 3;         // row within 8-row group
    const int sl = lane & 7;          // LDS slot within row
    const int u  = sl ^ rl;           // swizzle: slot sl holds source seg u = sl^(row&7)

    const bf16_t* asrc[4];
    const bf16_t* bsrc[4];
    bf16_t* alds[4];
    bf16_t* blds[4];
    #pragma unroll
    for (int i = 0; i < 4; ++i) {
        const int row = wave * 32 + i * 8 + rl;     // tile row 0..127
        const int m   = mtile * 128 + row;
        const int bb  = m / HW;
        const int rem = m - bb * HW;
        const int yy  = rem / IMG_W;
        const int xx  = rem - yy * IMG_W;
        asrc[i] = P + (((size_t)bb * PHW + yy * PW + xx) << 8) + u * 8;
        const int co = ntile * 128 + row;
        bsrc[i] = wt + (size_t)co * KDIM + u * 8;
        alds[i] = &Al[(wave * 32 + i * 8) * BK];    // plane-0 wave-uniform bases
        blds[i] = &Bl[(wave * 32 + i * 8) * BK];
    }

    // ---- compute roles: wave (wm,wn) owns 64x64; 2x2 of 32x32 MFMA tiles ----
    const int wm = wave & 1;
    const int wn = wave >> 1;
    const int ln = lane & 31;
    const int lh = lane >> 5;
    const int rx = ln & 7;            // row&7 for swizzled read

    f32x16 acc[2][2] = {};

    // prologue: stage pair 0 (r4-steps 0 -> plane 0, 1 -> plane 1)
    STAGE_P(0, 0);
    STAGE_P(1, 1);

    #pragma unroll 1
    for (int t = 0; t < ITER2; ++t) {
        __syncthreads();   // DMA for both planes complete in LDS

        // plane 0: read frags + MFMA
        bf16x8 af0[2][4], bf0[2][4];
        #pragma unroll
        for (int kk = 0; kk < 4; ++kk) {
            const int slot = ((kk * 2 + lh) ^ rx) * 8;
            #pragma unroll
            for (int g = 0; g < 2; ++g) {
                af0[g][kk] = *(const bf16x8*)(&Al[(wm * 64 + g * 32 + ln) * BK + slot]);
                bf0[g][kk] = *(const bf16x8*)(&Bl[(wn * 64 + g * 32 + ln) * BK + slot]);
            }
        }
        #pragma unroll
        for (int kk = 0; kk < 4; ++kk)
            #pragma unroll
            for (int g = 0; g < 2; ++g)
                #pragma unroll
                for (int h = 0; h < 2; ++h)
                    acc[g][h] = __builtin_amdgcn_mfma_f32_32x32x16_bf16(
                        af0[g][kk], bf0[h][kk], acc[g][h], 0, 0, 0);

        // plane 1: read frags
        bf16x8 af1[2][4], bf1[2][4];
        #pragma unroll
        for (int kk = 0; kk < 4; ++kk) {
            const int slot = ((kk * 2 + lh) ^ rx) * 8;
            #pragma unroll
            for (int g = 0; g < 2; ++g) {
                af1[g][kk] = *(const bf16x8*)(&Al[PLANE_E + (wm * 64 + g * 32 + ln) * BK + slot]);
                bf1[g][kk] = *(const bf16x8*)(&Bl[PLANE_E + (wn * 64 + g * 32 + ln) * BK + slot]);
            }
        }

        __syncthreads();   // all reads done; LDS free for next pair's DMA

        if (t + 1 < ITER2) {       // issue next pair's DMA BEFORE MFMA p1
            STAGE_P(2 * t + 2, 0);
            STAGE_P(2 * t + 3, 1);
        }

        // plane 1 MFMA (DMA flight overlaps this)
        #pragma unroll
        for (int kk = 0; kk < 4; ++kk)
            #pragma unroll
            for (int g = 0; g < 2; ++g)
                #pragma unroll
                for (int h = 0; h < 2; ++h)
                    acc[g][h] = __builtin_amdgcn_mfma_f32_32x32x16_bf16(
                        af1[g][kk], bf1[h][kk], acc[g][h], 0, 0, 0);
    }

    // ---- epilogue: 32x32 C/D layout col=lane&31, row=(reg&3)+8*(reg>>2)+4*lh ----
    const int mbase  = mtile * 128 + wm * 64;
    const int cobase = ntile * 128 + wn * 64;
    float bv[2];
    #pragma unroll
    for (int h = 0; h < 2; ++h) bv[h] = bias[cobase + h * 32 + ln];

    #pragma unroll
    for (int g = 0; g < 2; ++g) {
        #pragma unroll
        for (int reg = 0; reg < 16; ++reg) {
            const int mm = mbase + g * 32 + (reg & 3) + 8 * (reg >> 2) + 4 * lh;
            float* op = out + (size_t)mm * COUT + cobase + ln;
            op[0]  = acc[g][0][reg] + bv[0];
            op[32] = acc[g][1][reg] + bv[1];
        }
    }
}

// ---------- fallback conv (fp32 staging, round-1 validated) ----------
#define ASTR 40
#define BSTR 40
__global__ __launch_bounds__(256)
void conv_mfma(const float* __restrict__ in, const bf16_t* __restrict__ wt,
               const float* __restrict__ bias, float* __restrict__ out)
{
    __shared__ bf16_t Alf[128 * ASTR];
    __shared__ bf16_t Blf[128 * BSTR];

    const int tid   = threadIdx.x;
    const int ntile = blockIdx.x & 1;
    const int mtile = blockIdx.x >> 1;

    const int arow = tid >> 1;
    const int aseg = tid & 1;
    const int m    = mtile * 128 + arow;
    const int bb   = m / HW;
    const int rem  = m - bb * HW;
    const int yy   = rem / IMG_W;
    const int xx   = rem - yy * IMG_W;

    const bf16_t* wt_row = wt + (size_t)(ntile * 128 + arow) * KDIM + aseg * 16;

    const int wave = tid >> 6;
    const int lane = tid & 63;
    const int wm   = wave & 1;
    const int wn   = wave >> 1;
    const int lrow = lane & 15;
    const int q    = lane >> 4;

    f32x4 acc[4][4] = {};

    #pragma unroll 1
    for (int it = 0; it < 72; ++it) {
        const int tap = it >> 3;
        const int kh  = tap / 3;
        const int kw  = tap - kh * 3;
        const int ci0 = (it & 7) << 5;

        const int iy = yy + kh - 1;
        const int ix = xx + kw - 1;
        const bool valid = ((unsigned)iy < IMG_H) && ((unsigned)ix < IMG_W);

        f32x4 va[4] = {};
        if (valid) {
            const f32x4* src = (const f32x4*)(in +
                ((((size_t)bb * IMG_H + iy) * IMG_W + ix) * CIN + ci0 + aseg * 16));
            va[0] = src[0]; va[1] = src[1]; va[2] = src[2]; va[3] = src[3];
        }
        const uint4 wb0 = *(const uint4*)(wt_row + it * 32);
        const uint4 wb1 = *(const uint4*)(wt_row + it * 32 + 8);

        __syncthreads();

        bf16x8 pa0, pa1;
        #pragma unroll
        for (int e = 0; e < 8; ++e) pa0[e] = (bf16_t)va[e >> 2][e & 3];
        #pragma unroll
        for (int e = 0; e < 8; ++e) pa1[e] = (bf16_t)va[2 + (e >> 2)][e & 3];
        *(bf16x8*)(&Alf[arow * ASTR + aseg * 16])     = pa0;
        *(bf16x8*)(&Alf[arow * ASTR + aseg * 16 + 8]) = pa1;
        *(uint4*)(&Blf[arow * BSTR + aseg * 16])      = wb0;
        *(uint4*)(&Blf[arow * BSTR + aseg * 16 + 8])  = wb1;

        __syncthreads();

        bf16x8 af[4], bf[4];
        #pragma unroll
        for (int i = 0; i < 4; ++i)
            af[i] = *(const bf16x8*)(&Alf[(wm * 64 + i * 16 + lrow) * ASTR + q * 8]);
        #pragma unroll
        for (int j = 0; j < 4; ++j)
            bf[j] = *(const bf16x8*)(&Blf[(wn * 64 + j * 16 + lrow) * BSTR + q * 8]);

        #pragma unroll
        for (int i = 0; i < 4; ++i)
            #pragma unroll
            for (int j = 0; j < 4; ++j)
                acc[i][j] = __builtin_amdgcn_mfma_f32_16x16x32_bf16(af[i], bf[j], acc[i][j], 0, 0, 0);
    }

    const int co_base = ntile * 128 + wn * 64;
    float bv[4];
    #pragma unroll
    for (int j = 0; j < 4; ++j) bv[j] = bias[co_base + j * 16 + lrow];

    const int mrow_base = mtile * 128 + wm * 64;
    #pragma unroll
    for (int i = 0; i < 4; ++i) {
        #pragma unroll
        for (int rr = 0; rr < 4; ++rr) {
            const int mm = mrow_base + i * 16 + q * 4 + rr;
            float* op = out + (size_t)mm * COUT + co_base;
            #pragma unroll
            for (int j = 0; j < 4; ++j)
                op[j * 16 + lrow] = acc[i][j][rr] + bv[j];
        }
    }
}

extern "C" void kernel_launch(void* const* d_in, const int* in_sizes, int n_in,
                              void* d_out, int out_size, void* d_ws, size_t ws_size,
                              hipStream_t stream) {
    const float* inputs = (const float*)d_in[0];
    const float* kernel = (const float*)d_in[1];
    const float* bias   = (const float*)d_in[2];
    float*       outp   = (float*)d_out;

    const size_t p_elems = (size_t)IMG_B * PHW * CIN;               // 27,557,888
    const size_t p_bytes = p_elems * sizeof(bf16_t);                // 55.1 MB
    const size_t w_bytes = (size_t)KDIM * COUT * sizeof(bf16_t);    // 1.18 MB

    if (ws_size >= p_bytes + w_bytes) {
        bf16_t* pimg = (bf16_t*)d_ws;
        bf16_t* wt   = (bf16_t*)((char*)d_ws + p_bytes);
        prep_weights<<<WT_BLOCKS, 256, 0, stream>>>(kernel, wt);
        prep_border<<<BORDER_BLOCKS, 256, 0, stream>>>(pimg);
        prep_interior<<<INT_BLOCKS, 256, 0, stream>>>(inputs, pimg);
        conv_mfma_p<<<(M_TOT / 128) * 2, 256, 0, stream>>>(pimg, wt, bias, outp);
    } else {
        bf16_t* wt = (bf16_t*)d_ws;
        prep_weights<<<WT_BLOCKS, 256, 0, stream>>>(kernel, wt);
        conv_mfma<<<(M_TOT / 128) * 2, 256, 0, stream>>>(inputs, wt, bias, outp);
    }
}